// Round 13
// baseline (156.772 us; speedup 1.0000x reference)
//
#include <hip/hip_runtime.h>
#include <math.h>

// SparseMOELayer: N=65536 tokens, D=128, E=16 experts, top-3 routing.
// Outputs concat: logits[N*D] | importance_loss[1] | comb[N*E]
//
// R13 = R12 (measured optimum, e2e 155.6us) + two zero-risk latency cuts:
//  (a) k_prep 64->128 blocks (nt-range split): halves per-block prep latency.
//  (b) loadBp(Bf[0]) hoisted to k_fused entry: expert-0 B-loads in flight
//      through the whole gate phase (X3 stays the VGPR peak -> no cost).
// CEILING STATEMENT (why no further structural change):
//  e2e = k_fused(~76us) + ~80us fixed (harness/graph, constant across 3-
//  and 4-launch variants). k_fused = serial {fp64 gate ~30us VALU + MFMA
//  ~14us + staging/barrier latency}; inter-block overlap already captured.
//  Falsified on HW: R1 launch_bounds(256,4) (reg collapse, 1GB spill);
//  R3 fp64-W-LDS + per-block threadfence; R5 LDS shrink (occ flat);
//  R7 reg-diet 2x occupancy (dur worse); R8 kernel split (global
//  serialization); R9/R10 gate-under-expert jam (no intra-wave MFMA||VALU
//  mix reachable from HIP); R12 G2 bank remap (counter unchanged; the
//  2.26M conflicts are X2's, off critical path). fp32 gate rejected by
//  arithmetic: fp32 dot err ~1e-6, P(top3/4 gap<2e-6)~1e-5/token x 65536
//  -> E[routing flips]=0.65 -> ~50% fail at absmax 5.1e-2.
#define NTOK 65536
#define DD   128
#define NE   16
#define NK   3
#define TPB  64                    // tokens per block
#define NBLK (NTOK / TPB)          // 1024

#define OUT_LOSS ((size_t)NTOK * DD)
#define OUT_COMB ((size_t)NTOK * DD + 1)

typedef __bf16 bf16x8 __attribute__((ext_vector_type(8)));
typedef float  f32x4  __attribute__((ext_vector_type(4)));

__device__ __forceinline__ double softplus_d(double z) {
    return fmax(z, 0.0) + log1p(exp(-fabs(z)));
}

// ---------------------------------------------------------------------------
// K0: pack We[e][d][f] fp32 -> WeTp bf16, FRAGMENT-MAJOR:
//   WeTp[e][nt][s][lane][j]  (flat: e*16384 + (nt*4+s)*512 + lane*8 + j)
//   holds We[d = s*32 + (lane>>4)*8 + j][f = nt*16 + (lane&15)].
// R13: 128 blocks: (e = blk>>3, qd = (blk>>1)&3, nh = blk&1). Each block
// stages a 32x64 sub-panel (d-quarter qd, f-half nh) and writes 256
// fragment vectors (one per thread). Same output layout/values as R12's
// 64-block version. Block 0 zeroes imp_g.
// ---------------------------------------------------------------------------
__global__ __launch_bounds__(256) void k_prep(
    const float* __restrict__ We, __bf16* __restrict__ WeTp,
    float* __restrict__ imp_g)
{
    __shared__ __bf16 S[32][64 + 8];
    const int tid = threadIdx.x;
    const int e   = blockIdx.x >> 3;
    const int sub = blockIdx.x & 7;
    const int qd  = sub >> 1;                  // k-step s (d-quarter)
    const int nh  = sub & 1;                   // f-half: nt in [nh*4, nh*4+4)
    if (blockIdx.x == 0 && tid < NE) imp_g[tid] = 0.f;
    const size_t base = (size_t)e * DD * DD + (size_t)qd * 32 * DD
                      + (size_t)nh * 64;
    for (int i = tid; i < 32 * 64; i += 256) { // coalesced 256B row reads
        int dd = i >> 6, f = i & 63;
        S[dd][f] = (__bf16)We[base + (size_t)dd * DD + f];
    }
    __syncthreads();
    {
        int ntl  = tid >> 6;                   // 0..3 local n-tile
        int lane = tid & 63;
        int quad = lane >> 4, l15 = lane & 15;
        int fl = ntl * 16 + l15;               // local f (0..63)
        int nt = nh * 4 + ntl;                 // global n-tile
        bf16x8 vv;
        #pragma unroll
        for (int j = 0; j < 8; j++) vv[j] = S[quad * 8 + j][fl];
        *(bf16x8*)(WeTp + (size_t)e * 16384 +
                   ((size_t)(nt * 4 + qd) * 64 + lane) * 8) = vv;   // coalesced
    }
}

// ---------------------------------------------------------------------------
// Load one expert's B fragments (2 n-tiles x 4 k-steps) from packed WeTp.
// Each load: lane-consecutive 16B -> one 1KB coalesced transaction.
// ---------------------------------------------------------------------------
__device__ __forceinline__ void loadBp(
    bf16x8 (&dst)[2][4], const __bf16* __restrict__ WeTp,
    int e, int wid, int lane)
{
    const __bf16* b = WeTp + (size_t)e * 16384 + (size_t)lane * 8;
    #pragma unroll
    for (int t2 = 0; t2 < 2; t2++)
        #pragma unroll
        for (int s = 0; s < 4; s++)
            dst[t2][s] = *(const bf16x8*)(b + ((wid * 2 + t2) * 4 + s) * 512);
}

// ---------------------------------------------------------------------------
// K1: FUSED gate + expert. 64 tokens/block.
// Entry: issue expert-0 B prefetch, then stage x fp32 + gate weights.
// Gate fp64 dots fed from LDS (q-outer, W-hoisted; R0 op order ->
// bit-identical top-k) -> top-3 -> comb -> dense MFMA expert loop
// (register-resident, packed coalesced B) -> bias epilogue -> coalesced
// store (two 32-row halves).
// Importance: LDS partials -> one global atomicAdd per expert per block
// (imp_g zeroed by k_prep, stream-ordered).
// LDS (~59.4K, 2 blocks/CU; occupancy is register-pinned at 2 waves/SIMD):
//   union u: xs fp32 [64][132] (33.8K, entry..X2) | yh f32 (16.9K, X4)
//   union v: WgT+WnT (16.9K, dead after G2) | beS+combT (12.5K, G5..X4)
//   ga fp64 [64][17] dedicated (8.7K, G2..G4)
// MFMA 16x16x32 layouts (m89-verified):
//   A: lane l holds A[m=l&15][k=(l>>4)*8+j]; D: col=l&15, row=(l>>4)*4+reg
// ---------------------------------------------------------------------------
__global__ __launch_bounds__(256, 2) void k_fused(
    const float* __restrict__ x, const float* __restrict__ noise,
    const float* __restrict__ Wg, const float* __restrict__ bg,
    const float* __restrict__ Wn, const float* __restrict__ bn,
    const __bf16* __restrict__ WeTp, const float* __restrict__ be,
    float* __restrict__ out, float* __restrict__ imp_g)
{
    __shared__ union {
        float xs[TPB][DD + 4];                                         // 33.8K
        float yh[32][DD + 4];                                          // 16.9K
    } u;
    __shared__ union {
        struct { float WgT[NE][DD + 4]; float WnT[NE][DD + 4]; } w;    // 16.9K
        struct { float beS[NE][DD]; float combT[NE][TPB + 4]; } p;     // 12.5K
    } v;
    __shared__ double ga[TPB][NE + 1];                                 // 8.7K
    __shared__ float tkw[TPB][NK];
    __shared__ int   tke[TPB][NK];
    __shared__ float impS[NE];

    const int tid  = threadIdx.x;
    const int n0   = blockIdx.x * TPB;
    const int lane = tid & 63;
    const int wid  = tid >> 6;             // wave -> cols wid*32..+31
    const int l15  = lane & 15;
    const int quad = lane >> 4;
    const int e16  = tid & 15;             // gate-phase expert id
    const int tl   = tid >> 4;             // gate-phase token lane

    // ---- R13(b): issue expert-0 B prefetch; in flight through gate phases ----
    bf16x8 Bf[2][2][4];
    loadBp(Bf[0], WeTp, 0, wid, lane);

    // ---- G1: stage x fp32 (single global read) + gate weights; zero impS ----
    if (tid < NE) impS[tid] = 0.0f;
    for (int i = tid; i < DD * NE; i += 256) {
        int d = i >> 4, ee = i & 15;
        v.w.WgT[ee][d] = Wg[i];
        v.w.WnT[ee][d] = Wn[i];
    }
    for (int idx = tid; idx < TPB * DD / 4; idx += 256) {   // coalesced float4
        int t = idx >> 5, q = idx & 31;
        *(f32x4*)&u.xs[t][q * 4] =
            *(const f32x4*)(x + (size_t)(n0 + t) * DD + q * 4);
    }
    __syncthreads();

    // ---- G2+G3: fp64 dots, q-outer, fed from LDS ----
    // Per-chain fp64 op order identical to R0: chain j accumulates
    // x[4q+j]*w[4q+j] in ascending q; final (g0+g1)+(g2+g3); exact f32->f64
    // converts -> bit-identical gate values, identical top-k.
    {
        const f32x4* wgp = (const f32x4*)&v.w.WgT[e16][0];
        const f32x4* wnp = (const f32x4*)&v.w.WnT[e16][0];

        double Ga[4][4], Ha[4][4];
        #pragma unroll
        for (int g = 0; g < 4; g++)
            #pragma unroll
            for (int j = 0; j < 4; j++) { Ga[g][j] = 0.0; Ha[g][j] = 0.0; }

        #pragma unroll 2
        for (int q = 0; q < DD / 4; q++) {
            f32x4 wg = wgp[q], wn = wnp[q];
            double wg0 = (double)wg[0], wg1 = (double)wg[1];
            double wg2 = (double)wg[2], wg3 = (double)wg[3];
            double wn0 = (double)wn[0], wn1 = (double)wn[1];
            double wn2 = (double)wn[2], wn3 = (double)wn[3];
            f32x4 xv[4];
            #pragma unroll
            for (int g = 0; g < 4; g++)
                xv[g] = *(const f32x4*)&u.xs[tl * 4 + g][q * 4];
            #pragma unroll
            for (int g = 0; g < 4; g++) {
                double x0 = (double)xv[g][0], x1 = (double)xv[g][1];
                double x2 = (double)xv[g][2], x3 = (double)xv[g][3];
                Ga[g][0] += x0 * wg0; Ga[g][1] += x1 * wg1;
                Ga[g][2] += x2 * wg2; Ga[g][3] += x3 * wg3;
                Ha[g][0] += x0 * wn0; Ha[g][1] += x1 * wn1;
                Ha[g][2] += x2 * wn2; Ha[g][3] += x3 * wn3;
            }
        }

        const double bge = (double)bg[e16], bne = (double)bn[e16];
        #pragma unroll
        for (int g = 0; g < 4; g++) {
            int t = tl * 4 + g;
            double gsum = (Ga[g][0] + Ga[g][1]) + (Ga[g][2] + Ga[g][3]);
            double hsum = (Ha[g][0] + Ha[g][1]) + (Ha[g][2] + Ha[g][3]);
            double nz = (double)noise[(size_t)(n0 + t) * NE + e16];
            ga[t][e16] = gsum + bge + nz * softplus_d(hsum + bne);
        }
    }
    __syncthreads();

    // ---- G4: top-3 + softmax (64 threads) ----
    if (tid < TPB) {
        int t = tid;
        double vk[NK]; int ix[NK];
        unsigned taken = 0;
        for (int k = 0; k < NK; k++) {
            double best = -INFINITY; int bi = 0;
            for (int j = 0; j < NE; j++) {
                if (!((taken >> j) & 1u)) {
                    double gv = ga[t][j];
                    if (gv > best) { best = gv; bi = j; }  // strict >: low idx tie
                }
            }
            taken |= 1u << bi;
            vk[k] = best; ix[k] = bi;
        }
        double e1 = exp(vk[1] - vk[0]);
        double e2 = exp(vk[2] - vk[0]);
        double inv = 1.0 / (1.0 + e1 + e2);
        tke[t][0] = ix[0]; tke[t][1] = ix[1]; tke[t][2] = ix[2];
        tkw[t][0] = (float)inv;
        tkw[t][1] = (float)(e1 * inv);
        tkw[t][2] = (float)(e2 * inv);
    }
    __syncthreads();   // W (v.w) dead since G2 -> v.p reusable now

    // ---- G5: comb (global + LDS combT), impS, beS staging ----
    for (int g = 0; g < 4; g++) {
        int t = g * 16 + tl;
        float c = 0.f;
        if (tke[t][0] == e16) c = tkw[t][0];
        if (tke[t][1] == e16) c = tkw[t][1];
        if (tke[t][2] == e16) c = tkw[t][2];
        out[OUT_COMB + (size_t)(n0 + t) * NE + e16] = c;
        v.p.combT[e16][t] = c;
        if (c != 0.f) atomicAdd(&impS[e16], c);
    }
    for (int idx = tid; idx < NE * DD; idx += 256)      // stage be
        v.p.beS[idx >> 7][idx & 127] = be[idx];
    __syncthreads();

    // importance partials -> global (device-scope atomics)
    if (tid < NE) atomicAdd(&imp_g[tid], impS[tid]);

    // ---- X2: build bf16 A fragments from fp32 xs (read LDS once) ----
    // Same (__bf16) converts as the old restage path -> identical values.
    bf16x8 Af[4][4];
    #pragma unroll
    for (int a = 0; a < 4; a++)
        #pragma unroll
        for (int s = 0; s < 4; s++) {
            const float* src = &u.xs[a * 16 + l15][32 * s + quad * 8];
            f32x4 lo = *(const f32x4*)src;
            f32x4 hi = *(const f32x4*)(src + 4);
            bf16x8 vv;
            vv[0] = (__bf16)lo[0]; vv[1] = (__bf16)lo[1];
            vv[2] = (__bf16)lo[2]; vv[3] = (__bf16)lo[3];
            vv[4] = (__bf16)hi[0]; vv[5] = (__bf16)hi[1];
            vv[6] = (__bf16)hi[2]; vv[7] = (__bf16)hi[3];
            Af[a][s] = vv;
        }

    // ---- X3: expert loop, register-resident, dbuf coalesced B ----
    f32x4 logits[4][2];
    #pragma unroll
    for (int a = 0; a < 4; a++) {
        logits[a][0] = (f32x4){0.f, 0.f, 0.f, 0.f};
        logits[a][1] = (f32x4){0.f, 0.f, 0.f, 0.f};
    }

    #pragma unroll 2
    for (int e = 0; e < NE; e++) {
        const int cur = e & 1;
        if (e + 1 < NE) loadBp(Bf[cur ^ 1], WeTp, e + 1, wid, lane);

        f32x4 acc[4][2];
        #pragma unroll
        for (int a = 0; a < 4; a++) {
            acc[a][0] = (f32x4){0.f, 0.f, 0.f, 0.f};
            acc[a][1] = (f32x4){0.f, 0.f, 0.f, 0.f};
        }
        #pragma unroll
        for (int s = 0; s < 4; s++)        // s-outer: 8 indep chains
            #pragma unroll
            for (int a = 0; a < 4; a++) {
                acc[a][0] = __builtin_amdgcn_mfma_f32_16x16x32_bf16(
                    Af[a][s], Bf[cur][0][s], acc[a][0], 0, 0, 0);
                acc[a][1] = __builtin_amdgcn_mfma_f32_16x16x32_bf16(
                    Af[a][s], Bf[cur][1][s], acc[a][1], 0, 0, 0);
            }
        #pragma unroll
        for (int a = 0; a < 4; a++) {
            f32x4 cv = *(const f32x4*)&v.p.combT[e][a * 16 + quad * 4];
            #pragma unroll
            for (int r = 0; r < 4; r++) {
                logits[a][0][r] = fmaf(cv[r], acc[a][0][r], logits[a][0][r]);
                logits[a][1][r] = fmaf(cv[r], acc[a][1][r], logits[a][1][r]);
            }
        }
    }

    // ---- X4: bias epilogue + LDS-staged coalesced store (two halves) ----
    const int nA = wid * 32, nB = nA + 16;
    #pragma unroll 4
    for (int e = 0; e < NE; e++) {
        float bA = v.p.beS[e][nA + l15];
        float bB = v.p.beS[e][nB + l15];
        #pragma unroll
        for (int a = 0; a < 4; a++) {
            f32x4 cv = *(const f32x4*)&v.p.combT[e][a * 16 + quad * 4];
            #pragma unroll
            for (int r = 0; r < 4; r++) {
                logits[a][0][r] = fmaf(cv[r], bA, logits[a][0][r]);
                logits[a][1][r] = fmaf(cv[r], bB, logits[a][1][r]);
            }
        }
    }
    #pragma unroll
    for (int h = 0; h < 2; h++) {
        // h=0 barrier: ALL threads finished X2's xs reads (xs/yh union safe).
        __syncthreads();
        #pragma unroll
        for (int a2 = 0; a2 < 2; a2++) {
            const int a = h * 2 + a2;
            #pragma unroll
            for (int r = 0; r < 4; r++) {
                int row = a2 * 16 + quad * 4 + r;   // 0..31 within half
                u.yh[row][nA + l15] = logits[a][0][r];
                u.yh[row][nB + l15] = logits[a][1][r];
            }
        }
        __syncthreads();
        float4* op4 = (float4*)(out + ((size_t)n0 + h * 32) * DD);
        for (int idx = tid; idx < 32 * DD / 4; idx += 256) {
            int t = idx >> 5, q = idx & 31;
            op4[idx] = *(const float4*)&u.yh[t][q * 4];
        }
    }
}

// ---------------------------------------------------------------------------
// K2: loss from 16 globally-accumulated importances (atomic sums from k_fused).
// ---------------------------------------------------------------------------
__global__ __launch_bounds__(64) void k_loss(
    const float* __restrict__ imp_g, float* __restrict__ out)
{
    if (threadIdx.x == 0) {
        double mean = 0.0;
        for (int i = 0; i < NE; i++) mean += (double)imp_g[i];
        mean /= NE;
        double var = 0.0;
        for (int i = 0; i < NE; i++) {
            double d = (double)imp_g[i] - mean; var += d * d;
        }
        var /= (NE - 1);                    // ddof=1
        out[OUT_LOSS] = (float)(var / (mean * mean));
    }
}

// ---------------------------------------------------------------------------
extern "C" void kernel_launch(void* const* d_in, const int* in_sizes, int n_in,
                              void* d_out, int out_size, void* d_ws, size_t ws_size,
                              hipStream_t stream)
{
    (void)in_sizes; (void)n_in; (void)out_size; (void)ws_size;
    const float* x     = (const float*)d_in[0];
    const float* noise = (const float*)d_in[1];
    const float* Wg    = (const float*)d_in[2];
    const float* bg    = (const float*)d_in[3];
    const float* Wn    = (const float*)d_in[4];
    const float* bn    = (const float*)d_in[5];
    const float* We    = (const float*)d_in[6];
    const float* be    = (const float*)d_in[7];
    float* out = (float*)d_out;

    char*   ws    = (char*)d_ws;
    float*  imp_g = (float*)ws;                  // 64 B (16 floats)
    __bf16* WeTp  = (__bf16*)(ws + 1024);        // 512 KB, 16B-aligned

    hipLaunchKernelGGL(k_prep, dim3(128), dim3(256), 0, stream,
                       We, WeTp, imp_g);
    hipLaunchKernelGGL(k_fused, dim3(NBLK), dim3(256), 0, stream,
                       x, noise, Wg, bg, Wn, bn, WeTp, be, out, imp_g);
    hipLaunchKernelGGL(k_loss, dim3(1), dim3(64), 0, stream, imp_g, out);
}